// Round 22
// baseline (66.047 us; speedup 1.0000x reference)
//
#include <hip/hip_runtime.h>
#include <hip/hip_bf16.h>

#define TD_B 512

typedef __bf16 bf16x8 __attribute__((ext_vector_type(8)));
typedef __bf16 bf16x4 __attribute__((ext_vector_type(4)));
typedef float  f32x4  __attribute__((ext_vector_type(4)));

#define MFMA(a, b, c) __builtin_amdgcn_mfma_f32_16x16x32_bf16((a), (b), (c), 0, 0, 0)

__device__ __forceinline__ float sigf(float x)  { return 1.0f / (1.0f + __expf(-x)); }
__device__ __forceinline__ float tanhf_(float x){ return 2.0f / (1.0f + __expf(-2.0f * x)) - 1.0f; }

// LDS-only barrier: orders ds ops across waves WITHOUT draining global loads.
__device__ __forceinline__ void sync_lds() {
    __builtin_amdgcn_sched_barrier(0);
    asm volatile("s_waitcnt lgkmcnt(0)" ::: "memory");
    __builtin_amdgcn_s_barrier();
    __builtin_amdgcn_sched_barrier(0);
}

extern "C" __global__ void __launch_bounds__(256, 2)
traj_disc_kernel(const float* __restrict__ x, const float* __restrict__ dmat,
                 const float* __restrict__ bmat, const float* __restrict__ hmat,
                 const float* __restrict__ mask,
                 const float* __restrict__ emb_w, const float* __restrict__ emb_b,
                 const float* __restrict__ w_ih, const float* __restrict__ w_hh,
                 const float* __restrict__ b_ih, const float* __restrict__ b_hh,
                 const float* __restrict__ e2a_w, const float* __restrict__ e2a_b,
                 const float* __restrict__ dom,
                 const float* __restrict__ sp_w, const float* __restrict__ sp_b,
                 const float* __restrict__ a2e_w, const float* __restrict__ a2e_b,
                 const float* __restrict__ w1, const float* __restrict__ b1,
                 const float* __restrict__ w2, const float* __restrict__ b2,
                 const float* __restrict__ w3, const float* __restrict__ b3,
                 float* __restrict__ out)
{
    const int b    = blockIdx.x;
    const int tid  = threadIdx.x;
    const int lane = tid & 63;
    const int w    = tid >> 6;       // wave 0..3
    const int l15  = lane & 15;
    const int lg   = lane >> 4;      // 0..3

    __shared__ __bf16 sAin[32][72];   // 0-15 xe | 16-47 h | 48 ones | 49-63 zero
    __shared__ __bf16 sHl [32][40];
    __shared__ __bf16 sWN [32][40];
    __shared__ __bf16 sHaT[32][40];
    __shared__ __bf16 sEmb[32][40];
    __shared__ __bf16 sPA [32][72];   // 0-31 ha | 32-63 att
    __shared__ float  sMaskT[20][36];
    __shared__ float  sDom[144];
    __shared__ __bf16 z1bf[32][136];
    __shared__ __bf16 z2bf[32][136];
    __shared__ int    sFlag;

    // ---- staging ----
    if (tid == 0) sFlag = 1;
    for (int idx = tid; idx < 32 * 72; idx += 256)
        (&sAin[0][0])[idx] = (idx % 72 == 48) ? (__bf16)1.0f : (__bf16)0.0f;
    for (int idx = tid; idx < 640; idx += 256) {
        int tt = idx >> 5, n = idx & 31;
        sMaskT[tt][n] = mask[(b * 32 + n) * 20 + tt];
    }
    if (tid < 144) sDom[tid] = dom[tid];
    __syncthreads();
    // uniformity check (deterministic, input-dependent): dom all-equal AND mask all-ones
    {
        const float d0 = sDom[0];
        bool ok = true;
        for (int i = tid; i < 144; i += 256) ok &= (sDom[i] == d0);
        for (int i = tid; i < 640; i += 256) ok &= ((&sMaskT[0][0])[(i >> 5) * 36 + (i & 31)] == 1.0f);
        if (!ok) sFlag = 0;
    }

    // phase-A per-thread constants
    const int i0 = tid >> 3, p0 = tid & 7;
    const float dom0 = dom[0];
    const float ewa0 = emb_w[2 * p0],      ewa1 = emb_w[2 * p0 + 1];
    const float ewb0 = emb_w[16 + 2 * p0], ewb1 = emb_w[16 + 2 * p0 + 1];
    const float eb0  = emb_b[2 * p0],      eb1  = emb_b[2 * p0 + 1];

    // ---- transposed-gates A-fragments (gate-interleaved cols c=4h+g) ----
    bf16x8 Ag[2][2];
    #pragma unroll
    for (int mtl = 0; mtl < 2; ++mtl) {
        int c  = (2 * w + mtl) * 16 + l15;
        int cg = (c & 3) * 32 + (c >> 2);
        #pragma unroll
        for (int kt = 0; kt < 2; ++kt)
            #pragma unroll
            for (int j = 0; j < 8; ++j) {
                int k = kt * 32 + lg * 8 + j;
                float v;
                if (k < 16)       v = w_ih[k * 128 + cg];
                else if (k < 48)  v = w_hh[(k - 16) * 128 + cg];
                else if (k == 48) v = b_ih[cg] + b_hh[cg];
                else              v = 0.0f;
                Ag[mtl][kt][j] = (__bf16)v;
            }
    }
    // wave roles for C/D/E/F: row-half mtw, col-half ntw
    const int mtw = w >> 1, ntw = w & 1;
    const int cw  = ntw * 16 + l15;
    bf16x8 Be2a, Ba2e, Bsp[2];
    #pragma unroll
    for (int j = 0; j < 8; ++j) {
        Be2a[j] = (__bf16)e2a_w[(lg * 8 + j) * 32 + cw];
        Ba2e[j] = (__bf16)a2e_w[(lg * 8 + j) * 32 + cw];
    }
    #pragma unroll
    for (int kt = 0; kt < 2; ++kt)
        #pragma unroll
        for (int j = 0; j < 8; ++j)
            Bsp[kt][j] = (__bf16)sp_w[(kt * 32 + lg * 8 + j) * 32 + cw];
    const float bEw = e2a_b[cw], bSw = sp_b[cw], bAw = a2e_b[cw];

    float cst[2][2] = {{0.f, 0.f}, {0.f, 0.f}};  // cell state [mtl][nt], lane-local
    f32x4 accZ[2][2] = {};                       // online z1 [mt][ntp]
    bf16x8 Bw1cur[2];

    // incremental pointers (t-stride: dmat/bmat/hmat = 32 floats; x = 2; w1 = 4096)
    const float* dp = dmat + ((long)(b * 32 + i0) * 20) * 32 + 4 * p0;
    const float* bp = bmat + ((long)(b * 32 + i0) * 20) * 32 + 4 * p0;
    const float* hp = hmat + ((long)(b * 32 + i0) * 20) * 32 + 4 * p0;
    const float* xp = x + ((long)(b * 32 + i0) * 20) * 2;
    const float* w1p = w1 + lg * 8 * 128 + 32 * w + l15;

    // prefetch t=0 inputs
    float4 pdv = *(const float4*)dp;
    float4 pbv = *(const float4*)bp;
    float4 phv = *(const float4*)hp;
    float px0 = xp[0], px1 = xp[1];
    __syncthreads();
    const bool fast = (sFlag != 0);   // block-uniform

    #pragma unroll 1
    for (int t = 0; t < 20; ++t) {
        // ===== phase A: wmat+normalize (regs), wN/xe stores; prefetch t+1 =====
        {
            float4 dv = pdv, bv = pbv, hv = phv;
            float xx0 = px0, xx1 = px1;
            if (t < 19) {
                pdv = *(const float4*)(dp + 32); dp += 32;
                if (!fast) {
                    pbv = *(const float4*)(bp + 32); bp += 32;
                    phv = *(const float4*)(hp + 32); hp += 32;
                }
                px0 = xp[2]; px1 = xp[3]; xp += 2;
            }
            float wq[4];
            float inv;
            if (fast) {
                #pragma unroll
                for (int q = 0; q < 4; ++q) {
                    float v = dom0 - (&dv.x)[q];
                    wq[q] = v > 0.f ? v : 0.f;
                }
                float s = wq[0] + wq[1] + wq[2] + wq[3];
                s += __shfl_xor(s, 1); s += __shfl_xor(s, 2); s += __shfl_xor(s, 4);
                inv = 1.0f / (s + 1e-8f);
            } else {
                float4 mj = *(const float4*)&sMaskT[t][4 * p0];
                float  mi = sMaskT[t][i0];
                #pragma unroll
                for (int q = 0; q < 4; ++q) {
                    float bq = (&bv.x)[q], hq = (&hv.x)[q];
                    int ib = (int)floorf(bq * (1.0f / 30.0f)); ib = ib < 0 ? 0 : (ib > 11 ? 11 : ib);
                    int ih = (int)floorf(hq * (1.0f / 30.0f)); ih = ih < 0 ? 0 : (ih > 11 ? 11 : ih);
                    float v = sDom[ib * 12 + ih] - (&dv.x)[q];
                    v = v > 0.f ? v : 0.f;
                    wq[q] = v * (&mj.x)[q];
                }
                float s = wq[0] + wq[1] + wq[2] + wq[3];
                s += __shfl_xor(s, 1); s += __shfl_xor(s, 2); s += __shfl_xor(s, 4);
                inv = mi / (mi * s + 1e-8f);
            }
            bf16x4 wn4;
            #pragma unroll
            for (int q = 0; q < 4; ++q) wn4[q] = (__bf16)(wq[q] * inv);
            *(bf16x4*)&sWN[i0][4 * p0] = wn4;
            sAin[i0][2 * p0]     = (__bf16)(xx0 * ewa0 + xx1 * ewb0 + eb0);
            sAin[i0][2 * p0 + 1] = (__bf16)(xx0 * ewa1 + xx1 * ewb1 + eb1);
        }
        sync_lds();                                        // s1

        // ===== phase B: transposed gates + lane-local cell + online z1 + w1 stream =====
        {
            bf16x8 bxh[2][2];
            #pragma unroll
            for (int nt = 0; nt < 2; ++nt)
                #pragma unroll
                for (int kt = 0; kt < 2; ++kt)
                    bxh[nt][kt] = *(const bf16x8*)&sAin[nt * 16 + l15][kt * 32 + lg * 8];
            __builtin_amdgcn_s_setprio(1);
            if (t >= 1) {     // z1 += h_{t-1} @ w1[(t-1)*32:]
                bf16x8 az[2];
                #pragma unroll
                for (int mt = 0; mt < 2; ++mt)
                    az[mt] = *(const bf16x8*)&sAin[mt * 16 + l15][16 + lg * 8];
                #pragma unroll
                for (int mt = 0; mt < 2; ++mt)
                    #pragma unroll
                    for (int ntp = 0; ntp < 2; ++ntp)
                        accZ[mt][ntp] = MFMA(az[mt], Bw1cur[ntp], accZ[mt][ntp]);
            }
            #pragma unroll
            for (int mtl = 0; mtl < 2; ++mtl)
                #pragma unroll
                for (int nt = 0; nt < 2; ++nt) {
                    f32x4 cc = {0.f, 0.f, 0.f, 0.f};
                    cc = MFMA(Ag[mtl][0], bxh[nt][0], cc);
                    cc = MFMA(Ag[mtl][1], bxh[nt][1], cc);
                    float cn = sigf(cc[1]) * cst[mtl][nt] + sigf(cc[0]) * tanhf_(cc[2]);
                    cst[mtl][nt] = cn;
                    sHl[nt * 16 + l15][4 * (2 * w + mtl) + lg] = (__bf16)(sigf(cc[3]) * tanhf_(cn));
                }
            __builtin_amdgcn_s_setprio(0);
            #pragma unroll
            for (int ntp = 0; ntp < 2; ++ntp)     // stream w1 rows t*32.. (used t+1 / tail)
                #pragma unroll
                for (int j = 0; j < 8; ++j)
                    Bw1cur[ntp][j] = (__bf16)w1p[j * 128 + ntp * 16];
            w1p += 4096;
        }
        sync_lds();                                        // s2

        // ===== phase C: ha tile -> sPA[:,0:32], sHaT ; hoist D's wN read =====
        bf16x8 aW;   // carried into D
        {
            bf16x8 a = *(const bf16x8*)&sHl[mtw * 16 + l15][lg * 8];
            aW = *(const bf16x8*)&sWN[mtw * 16 + l15][lg * 8];   // hoisted (stable since s1)
            __builtin_amdgcn_s_setprio(1);
            f32x4 cc = {0.f, 0.f, 0.f, 0.f};
            cc = MFMA(a, Be2a, cc);
            bf16x4 tv;
            #pragma unroll
            for (int q = 0; q < 4; ++q) {
                float v = cc[q] + bEw;
                tv[q] = (__bf16)v;
                sPA[mtw * 16 + 4 * lg + q][cw] = (__bf16)v;
            }
            *(bf16x4*)&sHaT[cw][mtw * 16 + 4 * lg] = tv;
            __builtin_amdgcn_s_setprio(0);
        }
        sync_lds();                                        // s3

        // ===== phase D: att = wN @ ha ; hoist E's first MFMA (ha @ sp_top) =====
        f32x4 ccE;   // carried into E
        {
            bf16x8 bT = *(const bf16x8*)&sHaT[cw][lg * 8];
            bf16x8 a0 = *(const bf16x8*)&sPA[mtw * 16 + l15][lg * 8];  // ha, ready after s3
            __builtin_amdgcn_s_setprio(1);
            f32x4 cc = {0.f, 0.f, 0.f, 0.f};
            cc = MFMA(aW, bT, cc);
            f32x4 z0 = {0.f, 0.f, 0.f, 0.f};
            ccE = MFMA(a0, Bsp[0], z0);                               // E part 1 (ILP with att)
            #pragma unroll
            for (int q = 0; q < 4; ++q)
                sPA[mtw * 16 + 4 * lg + q][32 + cw] = (__bf16)cc[q];
            __builtin_amdgcn_s_setprio(0);
        }
        sync_lds();                                        // s4

        // ===== phase E: emb = tanh(ccE + att @ sp_bot + b) =====
        {
            bf16x8 a1 = *(const bf16x8*)&sPA[mtw * 16 + l15][32 + lg * 8];
            __builtin_amdgcn_s_setprio(1);
            f32x4 cc = MFMA(a1, Bsp[1], ccE);
            #pragma unroll
            for (int q = 0; q < 4; ++q)
                sEmb[mtw * 16 + 4 * lg + q][cw] = (__bf16)tanhf_(cc[q] + bSw);
            __builtin_amdgcn_s_setprio(0);
        }
        sync_lds();                                        // s5

        // ===== phase F: h_new = emb @ a2e + b -> sAin cols 16-47 =====
        {
            bf16x8 a = *(const bf16x8*)&sEmb[mtw * 16 + l15][lg * 8];
            __builtin_amdgcn_s_setprio(1);
            f32x4 cc = {0.f, 0.f, 0.f, 0.f};
            cc = MFMA(a, Ba2e, cc);
            #pragma unroll
            for (int q = 0; q < 4; ++q)
                sAin[mtw * 16 + 4 * lg + q][16 + cw] = (__bf16)(cc[q] + bAw);
            __builtin_amdgcn_s_setprio(0);
        }
        // no barrier here: next-iteration s1 orders F/A -> B(t+1); A(t+1) writes disjoint LDS
    }

    // ================= tail =================
    __syncthreads();
    // final z1 accumulate (h_19 with w1 rows 608-639)
    {
        bf16x8 az[2];
        #pragma unroll
        for (int mt = 0; mt < 2; ++mt)
            az[mt] = *(const bf16x8*)&sAin[mt * 16 + l15][16 + lg * 8];
        #pragma unroll
        for (int mt = 0; mt < 2; ++mt)
            #pragma unroll
            for (int ntp = 0; ntp < 2; ++ntp)
                accZ[mt][ntp] = MFMA(az[mt], Bw1cur[ntp], accZ[mt][ntp]);
    }
    // z1 = leaky(accZ + b1)
    #pragma unroll
    for (int mt = 0; mt < 2; ++mt)
        #pragma unroll
        for (int ntp = 0; ntp < 2; ++ntp) {
            int c = (2 * w + ntp) * 16 + l15;
            float bias = b1[c];
            #pragma unroll
            for (int q = 0; q < 4; ++q) {
                float v = accZ[mt][ntp][q] + bias;
                v = v > 0.f ? v : 0.2f * v;
                z1bf[mt * 16 + 4 * lg + q][c] = (__bf16)v;
            }
        }
    __syncthreads();

    // z2 = leaky(z1 @ w2 + b2), K=128
    {
        f32x4 c2[2][2] = {};
        #pragma unroll
        for (int kt = 0; kt < 4; ++kt) {
            bf16x8 a[2];
            #pragma unroll
            for (int mt = 0; mt < 2; ++mt)
                a[mt] = *(const bf16x8*)&z1bf[mt * 16 + l15][kt * 32 + lg * 8];
            bf16x8 bb[2];
            #pragma unroll
            for (int ntp = 0; ntp < 2; ++ntp) {
                int c = (2 * w + ntp) * 16 + l15;
                #pragma unroll
                for (int j = 0; j < 8; ++j)
                    bb[ntp][j] = (__bf16)w2[(kt * 32 + lg * 8 + j) * 128 + c];
            }
            #pragma unroll
            for (int mt = 0; mt < 2; ++mt)
                #pragma unroll
                for (int ntp = 0; ntp < 2; ++ntp)
                    c2[mt][ntp] = MFMA(a[mt], bb[ntp], c2[mt][ntp]);
        }
        #pragma unroll
        for (int mt = 0; mt < 2; ++mt)
            #pragma unroll
            for (int ntp = 0; ntp < 2; ++ntp) {
                int c = (2 * w + ntp) * 16 + l15;
                float bias = b2[c];
                #pragma unroll
                for (int q = 0; q < 4; ++q) {
                    float v = c2[mt][ntp][q] + bias;
                    v = v > 0.f ? v : 0.2f * v;
                    z2bf[mt * 16 + 4 * lg + q][c] = (__bf16)v;
                }
            }
    }
    __syncthreads();

    // z3 = sigmoid(z2 @ w3 + b3)
    {
        int n = tid >> 3, kg = tid & 7;
        bf16x8 v0 = *(const bf16x8*)&z2bf[n][kg * 16];
        bf16x8 v1 = *(const bf16x8*)&z2bf[n][kg * 16 + 8];
        float s = 0.f;
        #pragma unroll
        for (int j = 0; j < 8; ++j)
            s += (float)v0[j] * w3[kg * 16 + j] + (float)v1[j] * w3[kg * 16 + 8 + j];
        s += __shfl_xor(s, 1); s += __shfl_xor(s, 2); s += __shfl_xor(s, 4);
        if (kg == 0) out[b * 32 + n] = sigf(s + b3[0]);
    }
}

extern "C" void kernel_launch(void* const* d_in, const int* in_sizes, int n_in,
                              void* d_out, int out_size, void* d_ws, size_t ws_size,
                              hipStream_t stream) {
    (void)in_sizes; (void)n_in; (void)d_ws; (void)ws_size; (void)out_size;
    const float* x     = (const float*)d_in[0];
    const float* dmat  = (const float*)d_in[1];
    const float* bmat  = (const float*)d_in[2];
    const float* hmat  = (const float*)d_in[3];
    const float* mask  = (const float*)d_in[4];
    const float* emb_w = (const float*)d_in[5];
    const float* emb_b = (const float*)d_in[6];
    const float* w_ih  = (const float*)d_in[7];
    const float* w_hh  = (const float*)d_in[8];
    const float* b_ih  = (const float*)d_in[9];
    const float* b_hh  = (const float*)d_in[10];
    const float* e2a_w = (const float*)d_in[11];
    const float* e2a_b = (const float*)d_in[12];
    const float* dom   = (const float*)d_in[13];
    const float* sp_w  = (const float*)d_in[14];
    const float* sp_b  = (const float*)d_in[15];
    const float* a2e_w = (const float*)d_in[16];
    const float* a2e_b = (const float*)d_in[17];
    const float* w1    = (const float*)d_in[18];
    const float* b1    = (const float*)d_in[19];
    const float* w2    = (const float*)d_in[20];
    const float* b2    = (const float*)d_in[21];
    const float* w3    = (const float*)d_in[22];
    const float* b3    = (const float*)d_in[23];
    float* out = (float*)d_out;

    traj_disc_kernel<<<dim3(TD_B), dim3(256), 0, stream>>>(
        x, dmat, bmat, hmat, mask, emb_w, emb_b, w_ih, w_hh, b_ih, b_hh,
        e2a_w, e2a_b, dom, sp_w, sp_b, a2e_w, a2e_b,
        w1, b1, w2, b2, w3, b3, out);
}

// Round 23
// 65.747 us; speedup vs baseline: 1.0046x; 1.0046x over previous
//
#include <hip/hip_runtime.h>
#include <hip/hip_bf16.h>

#define TD_B 512

typedef __bf16 bf16x8 __attribute__((ext_vector_type(8)));
typedef __bf16 bf16x4 __attribute__((ext_vector_type(4)));
typedef float  f32x4  __attribute__((ext_vector_type(4)));

#define MFMA(a, b, c) __builtin_amdgcn_mfma_f32_16x16x32_bf16((a), (b), (c), 0, 0, 0)

__device__ __forceinline__ float sigf(float x)  { return 1.0f / (1.0f + __expf(-x)); }
__device__ __forceinline__ float tanhf_(float x){ return 2.0f / (1.0f + __expf(-2.0f * x)) - 1.0f; }

// LDS-only barrier: orders ds ops across waves WITHOUT draining global loads.
__device__ __forceinline__ void sync_lds() {
    __builtin_amdgcn_sched_barrier(0);
    asm volatile("s_waitcnt lgkmcnt(0)" ::: "memory");
    __builtin_amdgcn_s_barrier();
    __builtin_amdgcn_sched_barrier(0);
}

extern "C" __global__ void __launch_bounds__(256, 2)
traj_disc_kernel(const float* __restrict__ x, const float* __restrict__ dmat,
                 const float* __restrict__ bmat, const float* __restrict__ hmat,
                 const float* __restrict__ mask,
                 const float* __restrict__ emb_w, const float* __restrict__ emb_b,
                 const float* __restrict__ w_ih, const float* __restrict__ w_hh,
                 const float* __restrict__ b_ih, const float* __restrict__ b_hh,
                 const float* __restrict__ e2a_w, const float* __restrict__ e2a_b,
                 const float* __restrict__ dom,
                 const float* __restrict__ sp_w, const float* __restrict__ sp_b,
                 const float* __restrict__ a2e_w, const float* __restrict__ a2e_b,
                 const float* __restrict__ w1, const float* __restrict__ b1,
                 const float* __restrict__ w2, const float* __restrict__ b2,
                 const float* __restrict__ w3, const float* __restrict__ b3,
                 float* __restrict__ out)
{
    const int b    = blockIdx.x;
    const int tid  = threadIdx.x;
    const int lane = tid & 63;
    const int w    = tid >> 6;       // wave 0..3
    const int l15  = lane & 15;
    const int lg   = lane >> 4;      // 0..3

    __shared__ __bf16 sAin[32][72];   // 0-15 xe | 16-47 h | 48 ones | 49-63 zero
    __shared__ __bf16 sHl [32][40];
    __shared__ __bf16 sWN [32][40];
    __shared__ __bf16 sHaT[32][40];
    __shared__ __bf16 sEmb[32][40];
    __shared__ __bf16 sPA [32][72];   // 0-31 ha | 32-63 att
    __shared__ float  sMaskT[20][36];
    __shared__ float  sDom[144];
    __shared__ __bf16 z1bf[32][136];
    __shared__ __bf16 z2bf[32][136];
    __shared__ int    sFlag;

    // ---- staging ----
    if (tid == 0) sFlag = 1;
    for (int idx = tid; idx < 32 * 72; idx += 256)
        (&sAin[0][0])[idx] = (idx % 72 == 48) ? (__bf16)1.0f : (__bf16)0.0f;
    for (int idx = tid; idx < 640; idx += 256) {
        int tt = idx >> 5, n = idx & 31;
        sMaskT[tt][n] = mask[(b * 32 + n) * 20 + tt];
    }
    if (tid < 144) sDom[tid] = dom[tid];
    __syncthreads();
    // uniformity check (deterministic, input-dependent): dom all-equal AND mask all-ones
    {
        const float d0 = sDom[0];
        bool ok = true;
        for (int i = tid; i < 144; i += 256) ok &= (sDom[i] == d0);
        for (int i = tid; i < 640; i += 256) ok &= ((&sMaskT[0][0])[(i >> 5) * 36 + (i & 31)] == 1.0f);
        if (!ok) sFlag = 0;
    }

    // phase-A per-thread constants
    const int i0 = tid >> 3, p0 = tid & 7;
    const float dom0 = dom[0];
    const float ewa0 = emb_w[2 * p0],      ewa1 = emb_w[2 * p0 + 1];
    const float ewb0 = emb_w[16 + 2 * p0], ewb1 = emb_w[16 + 2 * p0 + 1];
    const float eb0  = emb_b[2 * p0],      eb1  = emb_b[2 * p0 + 1];

    // ---- transposed-gates A-fragments (gate-interleaved cols c=4h+g) ----
    bf16x8 Ag[2][2];
    #pragma unroll
    for (int mtl = 0; mtl < 2; ++mtl) {
        int c  = (2 * w + mtl) * 16 + l15;
        int cg = (c & 3) * 32 + (c >> 2);
        #pragma unroll
        for (int kt = 0; kt < 2; ++kt)
            #pragma unroll
            for (int j = 0; j < 8; ++j) {
                int k = kt * 32 + lg * 8 + j;
                float v;
                if (k < 16)       v = w_ih[k * 128 + cg];
                else if (k < 48)  v = w_hh[(k - 16) * 128 + cg];
                else if (k == 48) v = b_ih[cg] + b_hh[cg];
                else              v = 0.0f;
                Ag[mtl][kt][j] = (__bf16)v;
            }
    }
    // wave roles for C/D/E/F: row-half mtw, col-half ntw
    const int mtw = w >> 1, ntw = w & 1;
    const int cw  = ntw * 16 + l15;
    bf16x8 Be2a, Ba2e, Bsp[2];
    #pragma unroll
    for (int j = 0; j < 8; ++j) {
        Be2a[j] = (__bf16)e2a_w[(lg * 8 + j) * 32 + cw];
        Ba2e[j] = (__bf16)a2e_w[(lg * 8 + j) * 32 + cw];
    }
    #pragma unroll
    for (int kt = 0; kt < 2; ++kt)
        #pragma unroll
        for (int j = 0; j < 8; ++j)
            Bsp[kt][j] = (__bf16)sp_w[(kt * 32 + lg * 8 + j) * 32 + cw];
    const float bEw = e2a_b[cw], bSw = sp_b[cw], bAw = a2e_b[cw];

    float cst[2][2] = {{0.f, 0.f}, {0.f, 0.f}};  // cell state [mtl][nt], lane-local
    f32x4 accZ[2][2] = {};                       // online z1 [mt][ntp]
    bf16x8 Bw1cur[2];

    // incremental pointers (t-stride: dmat/bmat/hmat = 32 floats; x = 2; w1 = 4096)
    const float* dp = dmat + ((long)(b * 32 + i0) * 20) * 32 + 4 * p0;
    const float* bp = bmat + ((long)(b * 32 + i0) * 20) * 32 + 4 * p0;
    const float* hp = hmat + ((long)(b * 32 + i0) * 20) * 32 + 4 * p0;
    const float* xp = x + ((long)(b * 32 + i0) * 20) * 2;
    const float* w1p = w1 + lg * 8 * 128 + 32 * w + l15;

    // prefetch t=0 inputs
    float4 pdv = *(const float4*)dp;
    float4 pbv = *(const float4*)bp;
    float4 phv = *(const float4*)hp;
    float px0 = xp[0], px1 = xp[1];
    __syncthreads();
    const bool fast = (sFlag != 0);   // block-uniform

    #pragma unroll 1
    for (int t = 0; t < 20; ++t) {
        // ===== phase A: wmat+normalize (regs), wN/xe stores; prefetch t+1 =====
        {
            float4 dv = pdv, bv = pbv, hv = phv;
            float xx0 = px0, xx1 = px1;
            if (t < 19) {
                pdv = *(const float4*)(dp + 32); dp += 32;
                if (!fast) {
                    pbv = *(const float4*)(bp + 32); bp += 32;
                    phv = *(const float4*)(hp + 32); hp += 32;
                }
                px0 = xp[2]; px1 = xp[3]; xp += 2;
            }
            float wq[4];
            float inv;
            if (fast) {
                #pragma unroll
                for (int q = 0; q < 4; ++q) {
                    float v = dom0 - (&dv.x)[q];
                    wq[q] = v > 0.f ? v : 0.f;
                }
                float s = wq[0] + wq[1] + wq[2] + wq[3];
                s += __shfl_xor(s, 1); s += __shfl_xor(s, 2); s += __shfl_xor(s, 4);
                inv = 1.0f / (s + 1e-8f);
            } else {
                float4 mj = *(const float4*)&sMaskT[t][4 * p0];
                float  mi = sMaskT[t][i0];
                #pragma unroll
                for (int q = 0; q < 4; ++q) {
                    float bq = (&bv.x)[q], hq = (&hv.x)[q];
                    int ib = (int)floorf(bq * (1.0f / 30.0f)); ib = ib < 0 ? 0 : (ib > 11 ? 11 : ib);
                    int ih = (int)floorf(hq * (1.0f / 30.0f)); ih = ih < 0 ? 0 : (ih > 11 ? 11 : ih);
                    float v = sDom[ib * 12 + ih] - (&dv.x)[q];
                    v = v > 0.f ? v : 0.f;
                    wq[q] = v * (&mj.x)[q];
                }
                float s = wq[0] + wq[1] + wq[2] + wq[3];
                s += __shfl_xor(s, 1); s += __shfl_xor(s, 2); s += __shfl_xor(s, 4);
                inv = mi / (mi * s + 1e-8f);
            }
            bf16x4 wn4;
            #pragma unroll
            for (int q = 0; q < 4; ++q) wn4[q] = (__bf16)(wq[q] * inv);
            *(bf16x4*)&sWN[i0][4 * p0] = wn4;
            sAin[i0][2 * p0]     = (__bf16)(xx0 * ewa0 + xx1 * ewb0 + eb0);
            sAin[i0][2 * p0 + 1] = (__bf16)(xx0 * ewa1 + xx1 * ewb1 + eb1);
        }
        sync_lds();                                        // s1

        // ===== phase B: transposed gates + lane-local cell + online z1 + w1 stream =====
        {
            bf16x8 bxh[2][2];
            #pragma unroll
            for (int nt = 0; nt < 2; ++nt)
                #pragma unroll
                for (int kt = 0; kt < 2; ++kt)
                    bxh[nt][kt] = *(const bf16x8*)&sAin[nt * 16 + l15][kt * 32 + lg * 8];
            __builtin_amdgcn_s_setprio(1);
            if (t >= 1) {     // z1 += h_{t-1} @ w1[(t-1)*32:]
                bf16x8 az[2];
                #pragma unroll
                for (int mt = 0; mt < 2; ++mt)
                    az[mt] = *(const bf16x8*)&sAin[mt * 16 + l15][16 + lg * 8];
                #pragma unroll
                for (int mt = 0; mt < 2; ++mt)
                    #pragma unroll
                    for (int ntp = 0; ntp < 2; ++ntp)
                        accZ[mt][ntp] = MFMA(az[mt], Bw1cur[ntp], accZ[mt][ntp]);
            }
            #pragma unroll
            for (int mtl = 0; mtl < 2; ++mtl)
                #pragma unroll
                for (int nt = 0; nt < 2; ++nt) {
                    f32x4 cc = {0.f, 0.f, 0.f, 0.f};
                    cc = MFMA(Ag[mtl][0], bxh[nt][0], cc);
                    cc = MFMA(Ag[mtl][1], bxh[nt][1], cc);
                    float cn = sigf(cc[1]) * cst[mtl][nt] + sigf(cc[0]) * tanhf_(cc[2]);
                    cst[mtl][nt] = cn;
                    sHl[nt * 16 + l15][4 * (2 * w + mtl) + lg] = (__bf16)(sigf(cc[3]) * tanhf_(cn));
                }
            __builtin_amdgcn_s_setprio(0);
            #pragma unroll
            for (int ntp = 0; ntp < 2; ++ntp)     // stream w1 rows t*32.. (used t+1 / tail)
                #pragma unroll
                for (int j = 0; j < 8; ++j)
                    Bw1cur[ntp][j] = (__bf16)w1p[j * 128 + ntp * 16];
            w1p += 4096;
        }
        sync_lds();                                        // s2

        // ===== phase C: ha tile -> sPA[:,0:32], sHaT ; hoist D's wN read =====
        bf16x8 aW;   // carried into D
        {
            bf16x8 a = *(const bf16x8*)&sHl[mtw * 16 + l15][lg * 8];
            aW = *(const bf16x8*)&sWN[mtw * 16 + l15][lg * 8];   // hoisted (stable since s1)
            __builtin_amdgcn_s_setprio(1);
            f32x4 cc = {0.f, 0.f, 0.f, 0.f};
            cc = MFMA(a, Be2a, cc);
            bf16x4 tv;
            #pragma unroll
            for (int q = 0; q < 4; ++q) {
                float v = cc[q] + bEw;
                tv[q] = (__bf16)v;
                sPA[mtw * 16 + 4 * lg + q][cw] = (__bf16)v;
            }
            *(bf16x4*)&sHaT[cw][mtw * 16 + 4 * lg] = tv;
            __builtin_amdgcn_s_setprio(0);
        }
        sync_lds();                                        // s3

        // ===== phase D: att = wN @ ha ; hoist E's first MFMA (ha @ sp_top) =====
        f32x4 ccE;   // carried into E
        {
            bf16x8 bT = *(const bf16x8*)&sHaT[cw][lg * 8];
            bf16x8 a0 = *(const bf16x8*)&sPA[mtw * 16 + l15][lg * 8];  // ha, ready after s3
            __builtin_amdgcn_s_setprio(1);
            f32x4 cc = {0.f, 0.f, 0.f, 0.f};
            cc = MFMA(aW, bT, cc);
            f32x4 z0 = {0.f, 0.f, 0.f, 0.f};
            ccE = MFMA(a0, Bsp[0], z0);                               // E part 1 (ILP with att)
            #pragma unroll
            for (int q = 0; q < 4; ++q)
                sPA[mtw * 16 + 4 * lg + q][32 + cw] = (__bf16)cc[q];
            __builtin_amdgcn_s_setprio(0);
        }
        sync_lds();                                        // s4

        // ===== phase E: emb = tanh(ccE + att @ sp_bot + b) =====
        {
            bf16x8 a1 = *(const bf16x8*)&sPA[mtw * 16 + l15][32 + lg * 8];
            __builtin_amdgcn_s_setprio(1);
            f32x4 cc = MFMA(a1, Bsp[1], ccE);
            #pragma unroll
            for (int q = 0; q < 4; ++q)
                sEmb[mtw * 16 + 4 * lg + q][cw] = (__bf16)tanhf_(cc[q] + bSw);
            __builtin_amdgcn_s_setprio(0);
        }
        sync_lds();                                        // s5

        // ===== phase F: h_new = emb @ a2e + b -> sAin cols 16-47 =====
        {
            bf16x8 a = *(const bf16x8*)&sEmb[mtw * 16 + l15][lg * 8];
            __builtin_amdgcn_s_setprio(1);
            f32x4 cc = {0.f, 0.f, 0.f, 0.f};
            cc = MFMA(a, Ba2e, cc);
            #pragma unroll
            for (int q = 0; q < 4; ++q)
                sAin[mtw * 16 + 4 * lg + q][16 + cw] = (__bf16)(cc[q] + bAw);
            __builtin_amdgcn_s_setprio(0);
        }
        // no barrier here: next-iteration s1 orders F/A -> B(t+1); A(t+1) writes disjoint LDS
    }

    // ================= tail =================
    __syncthreads();
    // final z1 accumulate (h_19 with w1 rows 608-639)
    {
        bf16x8 az[2];
        #pragma unroll
        for (int mt = 0; mt < 2; ++mt)
            az[mt] = *(const bf16x8*)&sAin[mt * 16 + l15][16 + lg * 8];
        #pragma unroll
        for (int mt = 0; mt < 2; ++mt)
            #pragma unroll
            for (int ntp = 0; ntp < 2; ++ntp)
                accZ[mt][ntp] = MFMA(az[mt], Bw1cur[ntp], accZ[mt][ntp]);
    }
    // z1 = leaky(accZ + b1)
    #pragma unroll
    for (int mt = 0; mt < 2; ++mt)
        #pragma unroll
        for (int ntp = 0; ntp < 2; ++ntp) {
            int c = (2 * w + ntp) * 16 + l15;
            float bias = b1[c];
            #pragma unroll
            for (int q = 0; q < 4; ++q) {
                float v = accZ[mt][ntp][q] + bias;
                v = v > 0.f ? v : 0.2f * v;
                z1bf[mt * 16 + 4 * lg + q][c] = (__bf16)v;
            }
        }
    __syncthreads();

    // z2 = leaky(z1 @ w2 + b2), K=128
    {
        f32x4 c2[2][2] = {};
        #pragma unroll
        for (int kt = 0; kt < 4; ++kt) {
            bf16x8 a[2];
            #pragma unroll
            for (int mt = 0; mt < 2; ++mt)
                a[mt] = *(const bf16x8*)&z1bf[mt * 16 + l15][kt * 32 + lg * 8];
            bf16x8 bb[2];
            #pragma unroll
            for (int ntp = 0; ntp < 2; ++ntp) {
                int c = (2 * w + ntp) * 16 + l15;
                #pragma unroll
                for (int j = 0; j < 8; ++j)
                    bb[ntp][j] = (__bf16)w2[(kt * 32 + lg * 8 + j) * 128 + c];
            }
            #pragma unroll
            for (int mt = 0; mt < 2; ++mt)
                #pragma unroll
                for (int ntp = 0; ntp < 2; ++ntp)
                    c2[mt][ntp] = MFMA(a[mt], bb[ntp], c2[mt][ntp]);
        }
        #pragma unroll
        for (int mt = 0; mt < 2; ++mt)
            #pragma unroll
            for (int ntp = 0; ntp < 2; ++ntp) {
                int c = (2 * w + ntp) * 16 + l15;
                float bias = b2[c];
                #pragma unroll
                for (int q = 0; q < 4; ++q) {
                    float v = c2[mt][ntp][q] + bias;
                    v = v > 0.f ? v : 0.2f * v;
                    z2bf[mt * 16 + 4 * lg + q][c] = (__bf16)v;
                }
            }
    }
    __syncthreads();

    // z3 = sigmoid(z2 @ w3 + b3)
    {
        int n = tid >> 3, kg = tid & 7;
        bf16x8 v0 = *(const bf16x8*)&z2bf[n][kg * 16];
        bf16x8 v1 = *(const bf16x8*)&z2bf[n][kg * 16 + 8];
        float s = 0.f;
        #pragma unroll
        for (int j = 0; j < 8; ++j)
            s += (float)v0[j] * w3[kg * 16 + j] + (float)v1[j] * w3[kg * 16 + 8 + j];
        s += __shfl_xor(s, 1); s += __shfl_xor(s, 2); s += __shfl_xor(s, 4);
        if (kg == 0) out[b * 32 + n] = sigf(s + b3[0]);
    }
}

extern "C" void kernel_launch(void* const* d_in, const int* in_sizes, int n_in,
                              void* d_out, int out_size, void* d_ws, size_t ws_size,
                              hipStream_t stream) {
    (void)in_sizes; (void)n_in; (void)d_ws; (void)ws_size; (void)out_size;
    const float* x     = (const float*)d_in[0];
    const float* dmat  = (const float*)d_in[1];
    const float* bmat  = (const float*)d_in[2];
    const float* hmat  = (const float*)d_in[3];
    const float* mask  = (const float*)d_in[4];
    const float* emb_w = (const float*)d_in[5];
    const float* emb_b = (const float*)d_in[6];
    const float* w_ih  = (const float*)d_in[7];
    const float* w_hh  = (const float*)d_in[8];
    const float* b_ih  = (const float*)d_in[9];
    const float* b_hh  = (const float*)d_in[10];
    const float* e2a_w = (const float*)d_in[11];
    const float* e2a_b = (const float*)d_in[12];
    const float* dom   = (const float*)d_in[13];
    const float* sp_w  = (const float*)d_in[14];
    const float* sp_b  = (const float*)d_in[15];
    const float* a2e_w = (const float*)d_in[16];
    const float* a2e_b = (const float*)d_in[17];
    const float* w1    = (const float*)d_in[18];
    const float* b1    = (const float*)d_in[19];
    const float* w2    = (const float*)d_in[20];
    const float* b2    = (const float*)d_in[21];
    const float* w3    = (const float*)d_in[22];
    const float* b3    = (const float*)d_in[23];
    float* out = (float*)d_out;

    traj_disc_kernel<<<dim3(TD_B), dim3(256), 0, stream>>>(
        x, dmat, bmat, hmat, mask, emb_w, emb_b, w_ih, w_hh, b_ih, b_hh,
        e2a_w, e2a_b, dom, sp_w, sp_b, a2e_w, a2e_b,
        w1, b1, w2, b2, w3, b3, out);
}